// Round 1
// baseline (1873.269 us; speedup 1.0000x reference)
//
#include <hip/hip_runtime.h>
#include <hip/hip_bf16.h>

// GCN forward: h1 = relu((Anorm@x)@W1 + b1); h2 = relu((Anorm@h1)@W2 + b2);
// g = segmax(h2, batch); g = relu(g@Wg1+bg1); out = g@Wg2+bg2
// Anorm = D^-1/2 (A+I) D^-1/2, applied BEFORE the linear map (commutes).

#define NN 100000
#define NE 1600000
#define NG 512

__global__ void k_fill(float* p, float v, int n) {
    int i = blockIdx.x * blockDim.x + threadIdx.x;
    if (i < n) p[i] = v;
}

__global__ void k_deg(const int* __restrict__ dst, float* deg, int e) {
    int i = blockIdx.x * blockDim.x + threadIdx.x;
    if (i < e) atomicAdd(&deg[dst[i]], 1.0f);
}

__global__ void k_dinv(const float* __restrict__ deg, float* __restrict__ dinv, int n) {
    int i = blockIdx.x * blockDim.x + threadIdx.x;
    if (i < n) dinv[i] = rsqrtf(deg[i]);
}

// agg[n,f] = h[n,f] * (1/deg[n])   (self-loop term, dinv^2 = 1/deg)
template<int F>
__global__ void k_self_init(const float* __restrict__ h, const float* __restrict__ dinv,
                            float* __restrict__ agg, int total) {
    int i = blockIdx.x * blockDim.x + threadIdx.x;
    if (i >= total) return;
    int nn = i / F;
    float w = dinv[nn] * dinv[nn];
    agg[i] = h[i] * w;
}

// one wave per edge: agg[dst] += h[src] * dinv[src]*dinv[dst]
template<int F>
__global__ __launch_bounds__(256) void k_scatter(const float* __restrict__ h,
    const int* __restrict__ src, const int* __restrict__ dst,
    const float* __restrict__ dinv, float* __restrict__ agg, int e) {
    int e0 = blockIdx.x * 4 + (threadIdx.x >> 6);
    if (e0 >= e) return;
    int lane = threadIdx.x & 63;
    int s = src[e0], d = dst[e0];
    float w = dinv[s] * dinv[d];
    const float* hs = h + (size_t)s * F;
    float* ad = agg + (size_t)d * F;
#pragma unroll
    for (int f = lane; f < F; f += 64)
        atomicAdd(&ad[f], hs[f] * w);
}

// h1 = relu(agg1[ n,78 ] @ W1[78,128] + b1)
#define G1_NB 8
__global__ __launch_bounds__(128) void k_gemm1(const float* __restrict__ A,
    const float* __restrict__ W, const float* __restrict__ bias,
    float* __restrict__ out, int n) {
    __shared__ float Ws[78 * 128];
    __shared__ float rs[G1_NB * 78];
    int tid = threadIdx.x;
    int n0 = blockIdx.x * G1_NB;
    for (int i = tid; i < 78 * 128; i += 128) Ws[i] = W[i];
    for (int i = tid; i < G1_NB * 78; i += 128) {
        int nn = n0 + i / 78;
        rs[i] = (nn < n) ? A[(size_t)nn * 78 + i % 78] : 0.0f;
    }
    __syncthreads();
    float acc[G1_NB];
#pragma unroll
    for (int j = 0; j < G1_NB; j++) acc[j] = 0.0f;
    for (int k = 0; k < 78; k++) {
        float w = Ws[k * 128 + tid];
#pragma unroll
        for (int j = 0; j < G1_NB; j++) acc[j] += rs[j * 78 + k] * w;
    }
    float b = bias[tid];
    for (int j = 0; j < G1_NB; j++) {
        int nn = n0 + j;
        if (nn < n) out[(size_t)nn * 128 + tid] = fmaxf(acc[j] + b, 0.0f);
    }
}

// h2 = relu(agg2[n,128] @ W2[128,256] + b2); fused atomicMax pool into gmax[batch[n]]
#define G2_NB 8
__global__ __launch_bounds__(256) void k_gemm2_pool(const float* __restrict__ A,
    const float* __restrict__ W, const float* __restrict__ bias,
    const int* __restrict__ batch, unsigned* __restrict__ gmax, int n) {
    __shared__ float Ws[32 * 256];
    __shared__ float rs[G2_NB * 128];
    int tid = threadIdx.x;
    int n0 = blockIdx.x * G2_NB;
    for (int i = tid; i < G2_NB * 128; i += 256) {
        int nn = n0 + (i >> 7);
        rs[i] = (nn < n) ? A[(size_t)nn * 128 + (i & 127)] : 0.0f;
    }
    float acc[G2_NB];
#pragma unroll
    for (int j = 0; j < G2_NB; j++) acc[j] = 0.0f;
    for (int k0 = 0; k0 < 128; k0 += 32) {
        __syncthreads();   // first iter: also covers rs stores
        for (int i = tid; i < 32 * 256; i += 256)
            Ws[i] = W[(k0 + (i >> 8)) * 256 + (i & 255)];
        __syncthreads();
#pragma unroll
        for (int k = 0; k < 32; k++) {
            float w = Ws[k * 256 + tid];
#pragma unroll
            for (int j = 0; j < G2_NB; j++) acc[j] += rs[(j << 7) + k0 + k] * w;
        }
    }
    float b = bias[tid];
    for (int j = 0; j < G2_NB; j++) {
        int nn = n0 + j;
        if (nn < n) {
            float v = fmaxf(acc[j] + b, 0.0f);  // >= 0, so uint-max == float-max
            atomicMax(&gmax[(size_t)batch[nn] * 256 + tid], __float_as_uint(v));
        }
    }
}

// g1 = relu(gmax[512,256] @ Wg1[256,1024] + bg1); one block per graph
__global__ __launch_bounds__(256) void k_gemm3(const float* __restrict__ A,
    const float* __restrict__ W, const float* __restrict__ bias,
    float* __restrict__ out) {
    __shared__ float rs[256];
    int g = blockIdx.x, tid = threadIdx.x;
    rs[tid] = A[g * 256 + tid];
    __syncthreads();
    float acc[4] = {0.f, 0.f, 0.f, 0.f};
    for (int k = 0; k < 256; k++) {
        float a = rs[k];
#pragma unroll
        for (int j = 0; j < 4; j++) acc[j] += a * W[k * 1024 + tid + j * 256];
    }
#pragma unroll
    for (int j = 0; j < 4; j++) {
        int f = tid + j * 256;
        out[g * 1024 + f] = fmaxf(acc[j] + bias[f], 0.0f);
    }
}

// out = g1[512,1024] @ Wg2[1024,128] + bg2; one block per graph
__global__ __launch_bounds__(128) void k_gemm4(const float* __restrict__ A,
    const float* __restrict__ W, const float* __restrict__ bias,
    float* __restrict__ out) {
    __shared__ float rs[1024];
    int g = blockIdx.x, tid = threadIdx.x;
    for (int i = tid; i < 1024; i += 128) rs[i] = A[g * 1024 + i];
    __syncthreads();
    float acc = 0.0f;
    for (int k = 0; k < 1024; k++) acc += rs[k] * W[k * 128 + tid];
    out[g * 128 + tid] = acc + bias[tid];
}

extern "C" void kernel_launch(void* const* d_in, const int* in_sizes, int n_in,
                              void* d_out, int out_size, void* d_ws, size_t ws_size,
                              hipStream_t stream) {
    const float* x    = (const float*)d_in[0];
    const int*   ei   = (const int*)d_in[1];
    const int*   batch= (const int*)d_in[2];
    const float* W1   = (const float*)d_in[3];
    const float* b1   = (const float*)d_in[4];
    const float* W2   = (const float*)d_in[5];
    const float* b2   = (const float*)d_in[6];
    const float* Wg1  = (const float*)d_in[7];
    const float* bg1  = (const float*)d_in[8];
    const float* Wg2  = (const float*)d_in[9];
    const float* bg2  = (const float*)d_in[10];
    const int* src = ei;
    const int* dst = ei + NE;

    float* ws = (float*)d_ws;
    float* deg  = ws;  ws += NN;
    float* dinv = ws;  ws += NN;
    float* agg1 = ws;  ws += (size_t)NN * 78;
    float* h1   = ws;  ws += (size_t)NN * 128;
    float* agg2 = ws;  ws += (size_t)NN * 128;
    unsigned* gmax = (unsigned*)ws;  ws += (size_t)NG * 256;
    float* g1   = ws;  ws += (size_t)NG * 1024;
    // total ws use: ~137 MB

    // degrees (+1 self loop) and dinv
    k_fill<<<(NN + 255) / 256, 256, 0, stream>>>(deg, 1.0f, NN);
    k_deg<<<(NE + 255) / 256, 256, 0, stream>>>(dst, deg, NE);
    k_dinv<<<(NN + 255) / 256, 256, 0, stream>>>(deg, dinv, NN);

    // layer 1: aggregate x (78 feats), then GEMM -> h1 [N,128]
    k_self_init<78><<<(NN * 78 + 255) / 256, 256, 0, stream>>>(x, dinv, agg1, NN * 78);
    k_scatter<78><<<NE / 4, 256, 0, stream>>>(x, src, dst, dinv, agg1, NE);
    k_gemm1<<<NN / G1_NB, 128, 0, stream>>>(agg1, W1, b1, h1, NN);

    // layer 2: aggregate h1 (128 feats), then GEMM+pool
    k_self_init<128><<<(NN * 128 + 255) / 256, 256, 0, stream>>>(h1, dinv, agg2, NN * 128);
    k_scatter<128><<<NE / 4, 256, 0, stream>>>(h1, src, dst, dinv, agg2, NE);

    k_fill<<<(NG * 256 + 255) / 256, 256, 0, stream>>>((float*)gmax, 0.0f, NG * 256);
    k_gemm2_pool<<<NN / G2_NB, 256, 0, stream>>>(agg2, W2, b2, batch, gmax, NN);

    // MLP head
    k_gemm3<<<NG, 256, 0, stream>>>((const float*)gmax, Wg1, bg1, g1);
    k_gemm4<<<NG, 128, 0, stream>>>(g1, Wg2, bg2, (float*)d_out);
}

// Round 2
// 1091.609 us; speedup vs baseline: 1.7161x; 1.7161x over previous
//
#include <hip/hip_runtime.h>
#include <hip/hip_bf16.h>

// GCN forward, CSR-gather formulation:
//   agg = Anorm @ h  computed by per-dst gather over edges counting-sorted by dst
//   h1 = relu(agg1@W1+b1); h2 = relu(agg2@W2+b2) fused with segment-max pool;
//   head: relu(g@Wg1+bg1) @ Wg2 + bg2.
// Anorm = D^-1/2 (A+I) D^-1/2 applied BEFORE the linear map (commutes).

#define NN 100000
#define NE 1600000
#define NG 512
#define NBLK ((NN + 1023) / 1024)   // 98 scan blocks (1024 items each)

__global__ void k_zero_int(int* p, int n) {
    int i = blockIdx.x * blockDim.x + threadIdx.x;
    if (i < n) p[i] = 0;
}

__global__ void k_fill(float* p, float v, int n) {
    int i = blockIdx.x * blockDim.x + threadIdx.x;
    if (i < n) p[i] = v;
}

__global__ void k_hist(const int* __restrict__ dst, int* cnt, int e) {
    int i = blockIdx.x * blockDim.x + threadIdx.x;
    if (i < e) atomicAdd(&cnt[dst[i]], 1);
}

// dinv[i] = rsqrt(cnt[i] + 1)   (+1 self loop)
__global__ void k_dinv(const int* __restrict__ cnt, float* __restrict__ dinv, int n) {
    int i = blockIdx.x * blockDim.x + threadIdx.x;
    if (i < n) dinv[i] = rsqrtf((float)cnt[i] + 1.0f);
}

// pass A: per-block (1024-item) totals
__global__ __launch_bounds__(256) void k_bsum(const int* __restrict__ cnt, int* __restrict__ bsum) {
    __shared__ int s[256];
    int b = blockIdx.x, t = threadIdx.x;
    int base = b * 1024 + t * 4;
    int v = 0;
#pragma unroll
    for (int j = 0; j < 4; j++) { int i = base + j; if (i < NN) v += cnt[i]; }
    s[t] = v; __syncthreads();
    for (int off = 128; off > 0; off >>= 1) {
        if (t < off) s[t] += s[t + off];
        __syncthreads();
    }
    if (t == 0) bsum[b] = s[0];
}

// pass B: exclusive scan of the 98 block sums (single block); also set row_ptr[NN]
__global__ __launch_bounds__(128) void k_scan_bsum(int* bsum, int* row_ptr) {
    __shared__ int s[128];
    int t = threadIdx.x;
    int v = (t < NBLK) ? bsum[t] : 0;
    s[t] = v; __syncthreads();
    for (int off = 1; off < 128; off <<= 1) {
        int u = (t >= off) ? s[t - off] : 0;
        __syncthreads();
        s[t] += u;
        __syncthreads();
    }
    if (t < NBLK) bsum[t] = s[t] - v;   // exclusive
    if (t == 0) row_ptr[NN] = NE;
}

// pass C: per-block exclusive scan + offset -> row_ptr; also init cursor=row_ptr
__global__ __launch_bounds__(256) void k_scan_blocks(const int* __restrict__ cnt,
    const int* __restrict__ bsum, int* __restrict__ row_ptr, int* __restrict__ cursor) {
    __shared__ int s[256];
    int b = blockIdx.x, t = threadIdx.x;
    int base = b * 1024 + t * 4;
    int v[4]; int sum = 0;
#pragma unroll
    for (int j = 0; j < 4; j++) { int i = base + j; v[j] = (i < NN) ? cnt[i] : 0; sum += v[j]; }
    s[t] = sum; __syncthreads();
    for (int off = 1; off < 256; off <<= 1) {
        int u = (t >= off) ? s[t - off] : 0;
        __syncthreads();
        s[t] += u;
        __syncthreads();
    }
    int excl = s[t] - sum + bsum[b];
#pragma unroll
    for (int j = 0; j < 4; j++) {
        int i = base + j;
        if (i < NN) { row_ptr[i] = excl; cursor[i] = excl; excl += v[j]; }
    }
}

// counting-sort fill: src_s[pos] = src, w_s[pos] = dinv[src]*dinv[dst]
__global__ void k_fillslots(const int* __restrict__ src, const int* __restrict__ dst,
    const float* __restrict__ dinv, int* cursor,
    int* __restrict__ src_s, float* __restrict__ w_s, int e) {
    int i = blockIdx.x * blockDim.x + threadIdx.x;
    if (i >= e) return;
    int s = src[i], d = dst[i];
    int pos = atomicAdd(&cursor[d], 1);
    src_s[pos] = s;
    w_s[pos] = dinv[s] * dinv[d];
}

// one wave per node: agg[n] = h[n]*dinv[n]^2 + sum_e w_e * h[src_e]   (F=78)
__global__ __launch_bounds__(256) void k_gather78(const float* __restrict__ h,
    const int* __restrict__ rp, const int* __restrict__ src_s, const float* __restrict__ w_s,
    const float* __restrict__ dinv, float* __restrict__ agg) {
    int n = blockIdx.x * 4 + (threadIdx.x >> 6);
    if (n >= NN) return;
    int l = threadIdx.x & 63;
    float di = dinv[n], sw = di * di;
    const float* hn = h + (size_t)n * 78;
    float a0 = hn[l] * sw;
    float a1 = (l < 14) ? hn[64 + l] * sw : 0.0f;
    int e1 = rp[n + 1];
    for (int e = rp[n]; e < e1; e++) {
        int s = src_s[e]; float w = w_s[e];
        const float* hs = h + (size_t)s * 78;
        a0 += hs[l] * w;
        if (l < 14) a1 += hs[64 + l] * w;
    }
    float* an = agg + (size_t)n * 78;
    an[l] = a0;
    if (l < 14) an[64 + l] = a1;
}

// same, F=128, float2 per lane
__global__ __launch_bounds__(256) void k_gather128(const float* __restrict__ h,
    const int* __restrict__ rp, const int* __restrict__ src_s, const float* __restrict__ w_s,
    const float* __restrict__ dinv, float* __restrict__ agg) {
    int n = blockIdx.x * 4 + (threadIdx.x >> 6);
    if (n >= NN) return;
    int l = threadIdx.x & 63;
    float di = dinv[n], sw = di * di;
    float2 hv = ((const float2*)(h + (size_t)n * 128))[l];
    float ax = hv.x * sw, ay = hv.y * sw;
    int e1 = rp[n + 1];
    for (int e = rp[n]; e < e1; e++) {
        int s = src_s[e]; float w = w_s[e];
        float2 v = ((const float2*)(h + (size_t)s * 128))[l];
        ax += v.x * w; ay += v.y * w;
    }
    float2 o; o.x = ax; o.y = ay;
    ((float2*)(agg + (size_t)n * 128))[l] = o;
}

// h1 = relu(agg1[n,78] @ W1[78,128] + b1)
#define G1_NB 8
__global__ __launch_bounds__(128) void k_gemm1(const float* __restrict__ A,
    const float* __restrict__ W, const float* __restrict__ bias,
    float* __restrict__ out, int n) {
    __shared__ float Ws[78 * 128];
    __shared__ float rs[G1_NB * 78];
    int tid = threadIdx.x;
    int n0 = blockIdx.x * G1_NB;
    for (int i = tid; i < 78 * 128; i += 128) Ws[i] = W[i];
    for (int i = tid; i < G1_NB * 78; i += 128) {
        int nn = n0 + i / 78;
        rs[i] = (nn < n) ? A[(size_t)nn * 78 + i % 78] : 0.0f;
    }
    __syncthreads();
    float acc[G1_NB];
#pragma unroll
    for (int j = 0; j < G1_NB; j++) acc[j] = 0.0f;
    for (int k = 0; k < 78; k++) {
        float w = Ws[k * 128 + tid];
#pragma unroll
        for (int j = 0; j < G1_NB; j++) acc[j] += rs[j * 78 + k] * w;
    }
    float b = bias[tid];
    for (int j = 0; j < G1_NB; j++) {
        int nn = n0 + j;
        if (nn < n) out[(size_t)nn * 128 + tid] = fmaxf(acc[j] + b, 0.0f);
    }
}

// h2 = relu(agg2[n,128] @ W2[128,256] + b2); fused atomicMax pool into gmax[batch[n]]
#define G2_NB 8
__global__ __launch_bounds__(256) void k_gemm2_pool(const float* __restrict__ A,
    const float* __restrict__ W, const float* __restrict__ bias,
    const int* __restrict__ batch, unsigned* __restrict__ gmax, int n) {
    __shared__ float Ws[32 * 256];
    __shared__ float rs[G2_NB * 128];
    int tid = threadIdx.x;
    int n0 = blockIdx.x * G2_NB;
    for (int i = tid; i < G2_NB * 128; i += 256) {
        int nn = n0 + (i >> 7);
        rs[i] = (nn < n) ? A[(size_t)nn * 128 + (i & 127)] : 0.0f;
    }
    float acc[G2_NB];
#pragma unroll
    for (int j = 0; j < G2_NB; j++) acc[j] = 0.0f;
    for (int k0 = 0; k0 < 128; k0 += 32) {
        __syncthreads();   // first iter: also covers rs stores
        for (int i = tid; i < 32 * 256; i += 256)
            Ws[i] = W[(k0 + (i >> 8)) * 256 + (i & 255)];
        __syncthreads();
#pragma unroll
        for (int k = 0; k < 32; k++) {
            float w = Ws[k * 256 + tid];
#pragma unroll
            for (int j = 0; j < G2_NB; j++) acc[j] += rs[(j << 7) + k0 + k] * w;
        }
    }
    float b = bias[tid];
    for (int j = 0; j < G2_NB; j++) {
        int nn = n0 + j;
        if (nn < n) {
            float v = fmaxf(acc[j] + b, 0.0f);  // >= 0, so uint-max == float-max
            atomicMax(&gmax[(size_t)batch[nn] * 256 + tid], __float_as_uint(v));
        }
    }
}

// g1 = relu(gmax[512,256] @ Wg1[256,1024] + bg1); one block per graph
__global__ __launch_bounds__(256) void k_gemm3(const float* __restrict__ A,
    const float* __restrict__ W, const float* __restrict__ bias,
    float* __restrict__ out) {
    __shared__ float rs[256];
    int g = blockIdx.x, tid = threadIdx.x;
    rs[tid] = A[g * 256 + tid];
    __syncthreads();
    float acc[4] = {0.f, 0.f, 0.f, 0.f};
    for (int k = 0; k < 256; k++) {
        float a = rs[k];
#pragma unroll
        for (int j = 0; j < 4; j++) acc[j] += a * W[k * 1024 + tid + j * 256];
    }
#pragma unroll
    for (int j = 0; j < 4; j++) {
        int f = tid + j * 256;
        out[g * 1024 + f] = fmaxf(acc[j] + bias[f], 0.0f);
    }
}

// out = g1[512,1024] @ Wg2[1024,128] + bg2; one block per graph
__global__ __launch_bounds__(128) void k_gemm4(const float* __restrict__ A,
    const float* __restrict__ W, const float* __restrict__ bias,
    float* __restrict__ out) {
    __shared__ float rs[1024];
    int g = blockIdx.x, tid = threadIdx.x;
    for (int i = tid; i < 1024; i += 128) rs[i] = A[g * 1024 + i];
    __syncthreads();
    float acc = 0.0f;
    for (int k = 0; k < 1024; k++) acc += rs[k] * W[k * 128 + tid];
    out[g * 128 + tid] = acc + bias[tid];
}

extern "C" void kernel_launch(void* const* d_in, const int* in_sizes, int n_in,
                              void* d_out, int out_size, void* d_ws, size_t ws_size,
                              hipStream_t stream) {
    const float* x    = (const float*)d_in[0];
    const int*   ei   = (const int*)d_in[1];
    const int*   batch= (const int*)d_in[2];
    const float* W1   = (const float*)d_in[3];
    const float* b1   = (const float*)d_in[4];
    const float* W2   = (const float*)d_in[5];
    const float* b2   = (const float*)d_in[6];
    const float* Wg1  = (const float*)d_in[7];
    const float* bg1  = (const float*)d_in[8];
    const float* Wg2  = (const float*)d_in[9];
    const float* bg2  = (const float*)d_in[10];
    const int* src = ei;
    const int* dst = ei + NE;

    // workspace layout (all offsets in 4-byte words, 16B-aligned blocks)
    char* w8 = (char*)d_ws;
    int*   cnt     = (int*)w8;                 w8 += (size_t)NN * 4;
    int*   row_ptr = (int*)w8;                 w8 += (size_t)(NN + 4) * 4;
    int*   cursor  = (int*)w8;                 w8 += (size_t)NN * 4;
    int*   bsum    = (int*)w8;                 w8 += 128 * 4;
    int*   src_s   = (int*)w8;                 w8 += (size_t)NE * 4;
    float* w_s     = (float*)w8;               w8 += (size_t)NE * 4;
    float* dinv    = (float*)w8;               w8 += (size_t)NN * 4;
    float* agg1    = (float*)w8;               w8 += (size_t)NN * 78 * 4;
    float* h1      = (float*)w8;               w8 += (size_t)NN * 128 * 4;
    float* agg2    = (float*)w8;               w8 += (size_t)NN * 128 * 4;
    unsigned* gmax = (unsigned*)w8;            w8 += (size_t)NG * 256 * 4;
    float* g1      = (float*)w8;               w8 += (size_t)NG * 1024 * 4;
    // total ~151 MB

    // --- CSR build (counting sort by dst) ---
    k_zero_int<<<(NN + 255) / 256, 256, 0, stream>>>(cnt, NN);
    k_hist<<<(NE + 255) / 256, 256, 0, stream>>>(dst, cnt, NE);
    k_dinv<<<(NN + 255) / 256, 256, 0, stream>>>(cnt, dinv, NN);
    k_bsum<<<NBLK, 256, 0, stream>>>(cnt, bsum);
    k_scan_bsum<<<1, 128, 0, stream>>>(bsum, row_ptr);
    k_scan_blocks<<<NBLK, 256, 0, stream>>>(cnt, bsum, row_ptr, cursor);
    k_fillslots<<<(NE + 255) / 256, 256, 0, stream>>>(src, dst, dinv, cursor, src_s, w_s, NE);

    // --- layer 1: gather x (78 feats), GEMM -> h1 [N,128] ---
    k_gather78<<<NN / 4, 256, 0, stream>>>(x, row_ptr, src_s, w_s, dinv, agg1);
    k_gemm1<<<NN / G1_NB, 128, 0, stream>>>(agg1, W1, b1, h1, NN);

    // --- layer 2: gather h1 (128 feats), GEMM + max-pool ---
    k_gather128<<<NN / 4, 256, 0, stream>>>(h1, row_ptr, src_s, w_s, dinv, agg2);
    k_fill<<<(NG * 256 + 255) / 256, 256, 0, stream>>>((float*)gmax, 0.0f, NG * 256);
    k_gemm2_pool<<<NN / G2_NB, 256, 0, stream>>>(agg2, W2, b2, batch, gmax, NN);

    // --- MLP head ---
    k_gemm3<<<NG, 256, 0, stream>>>((const float*)gmax, Wg1, bg1, g1);
    k_gemm4<<<NG, 128, 0, stream>>>(g1, Wg2, bg2, (float*)d_out);
}